// Round 7
// baseline (661.895 us; speedup 1.0000x reference)
//
#include <hip/hip_runtime.h>

#define HH 128
static constexpr int kN0 = 100000;
static constexpr int kC1 = 10000;
static constexpr int kC2 = 1000;

// Contiguous bin layout for the 5 CSR segments:
// [bins0 (kN0) | bins1 (kC1) | bins2 (kC2) | binsP1 (kC1) | binsP2 (kC2)]
static constexpr int B0 = kN0;              // 100000
static constexpr int B1 = B0 + kC1;         // 110000
static constexpr int B2 = B1 + kC2;         // 111000
static constexpr int B3 = B2 + kC1;         // 121000
static constexpr int NTOT = B3 + kC2;       // 122000

// Variable-width buckets, ~uniform ITEM count:
static constexpr int NB0 = (kN0 + 127) / 128;   // 782
static constexpr int NB1 = (kC1 + 7) / 8;       // 1250
static constexpr int NB2 = kC2;                 // 1000
static constexpr int NBP1 = (kC1 + 127) / 128;  // 79
static constexpr int NBP2 = (kC2 + 15) / 16;    // 63
static constexpr int Q0 = NB0;                  // 782
static constexpr int Q1 = Q0 + NB1;             // 2032
static constexpr int Q2 = Q1 + NB2;             // 3032
static constexpr int Q3 = Q2 + NBP1;            // 3111
static constexpr int NBK = Q3 + NBP2;           // 3174

__device__ __forceinline__ int bucket_of(int bin) {
  if (bin < B0) return bin >> 7;
  if (bin < B1) return Q0 + ((bin - B0) >> 3);
  if (bin < B2) return Q1 + (bin - B1);
  if (bin < B3) return Q2 + ((bin - B2) >> 7);
  return Q3 + ((bin - B3) >> 4);
}

// bf16x2 helpers
__device__ __forceinline__ unsigned int f2_to_bf2(float a, float b) {
  unsigned int ua = __float_as_uint(a);
  unsigned int ub = __float_as_uint(b);
  ua = (ua + 0x7fffu + ((ua >> 16) & 1u)) >> 16;
  ub = (ub + 0x7fffu + ((ub >> 16) & 1u)) & 0xffff0000u;
  return ua | ub;
}
__device__ __forceinline__ unsigned short f2bf(float f) {
  unsigned int u = __float_as_uint(f);
  u = (u + 0x7fffu + ((u >> 16) & 1u)) >> 16;
  return (unsigned short)u;
}
__device__ __forceinline__ float bf2f(unsigned short s) {
  return __uint_as_float(((unsigned int)s) << 16);
}

using bf16x8 = __attribute__((ext_vector_type(8))) short;
using f32x4 = __attribute__((ext_vector_type(4))) float;

// ---------------- P1: bucket histogram ----------------
__global__ __launch_bounds__(256) void p1_kernel(const int* __restrict__ col0,
                                                 const int* __restrict__ col1,
                                                 const int* __restrict__ col2,
                                                 const int* __restrict__ cl1,
                                                 const int* __restrict__ cl2,
                                                 int E0, int E1, int E2,
                                                 int* __restrict__ bucketCnt) {
  __shared__ int h[NBK];
  for (int i = threadIdx.x; i < NBK; i += 256) h[i] = 0;
  __syncthreads();
  int T0 = E0, T1 = T0 + E1, T2 = T1 + E2, T3 = T2 + kN0, T4 = T3 + kC1;
  for (int g = blockIdx.x * 256 + threadIdx.x; g < T4; g += gridDim.x * 256) {
    int bin;
    if (g < T0)      bin = col0[g];
    else if (g < T1) bin = B0 + col1[g - T0];
    else if (g < T2) bin = B1 + col2[g - T1];
    else if (g < T3) bin = B2 + cl1[g - T2];
    else             bin = B3 + cl2[g - T3];
    atomicAdd(&h[bucket_of(bin)], 1);
  }
  __syncthreads();
  for (int i = threadIdx.x; i < NBK; i += 256) {
    int c = h[i];
    if (c) atomicAdd(&bucketCnt[i], c);
  }
}

// ---------------- P2: scan bucket counts ----------------
__global__ __launch_bounds__(1024) void p2_kernel(const int* __restrict__ bucketCnt,
                                                  int* __restrict__ bucketStart,
                                                  int* __restrict__ cursor,
                                                  int* __restrict__ startsg, int T) {
  int t = threadIdx.x;
  int v[4]; int s = 0;
#pragma unroll
  for (int j = 0; j < 4; j++) {
    int i = t * 4 + j;
    v[j] = (i < NBK) ? bucketCnt[i] : 0;
    s += v[j];
  }
  int lane = t & 63, w = t >> 6;
  int incl = s;
  for (int o = 1; o < 64; o <<= 1) { int u = __shfl_up(incl, o); if (lane >= o) incl += u; }
  __shared__ int wt[16];
  if (lane == 63) wt[w] = incl;
  __syncthreads();
  if (t == 0) { int run = 0; for (int i = 0; i < 16; i++) { int c = wt[i]; wt[i] = run; run += c; } }
  __syncthreads();
  int ex = wt[w] + incl - s;
#pragma unroll
  for (int j = 0; j < 4; j++) {
    int i = t * 4 + j;
    if (i < NBK) { bucketStart[i] = ex; cursor[i] = ex; }
    ex += v[j];
  }
  if (t == 0) { bucketStart[NBK] = T; startsg[NTOT] = T; }
}

// ---------------- P3: partition into buckets (int4 payload, single 16B store) ----
__global__ __launch_bounds__(256) void p3_kernel(const int* __restrict__ col0,
                                                 const int* __restrict__ col1,
                                                 const int* __restrict__ col2,
                                                 const int* __restrict__ cl1,
                                                 const int* __restrict__ cl2,
                                                 const int* __restrict__ row0,
                                                 const int* __restrict__ row1,
                                                 const int* __restrict__ row2,
                                                 const float* __restrict__ ew1,
                                                 const float* __restrict__ ew2,
                                                 int E0, int E1, int E2,
                                                 int* __restrict__ cursor,
                                                 int4* __restrict__ part) {
  __shared__ int h[NBK];
  __shared__ int gbase[NBK];
  for (int i = threadIdx.x; i < NBK; i += 256) h[i] = 0;
  __syncthreads();
  int T0 = E0, T1 = T0 + E1, T2 = T1 + E2, T3 = T2 + kN0, T4 = T3 + kC1;
  int base = blockIdx.x * 4096;
  int bins[16], srcs[16], rk[16];
  float wv[16];
#pragma unroll
  for (int j = 0; j < 16; j++) {
    int g = base + threadIdx.x + j * 256;
    int bin = -1, src = 0; float w = 0.f;
    if (g < T4) {
      if (g < T0) { bin = col0[g]; src = row0[g]; }
      else if (g < T1) { int e = g - T0; bin = B0 + col1[e]; src = row1[e]; w = ew1[e]; }
      else if (g < T2) { int e = g - T1; bin = B1 + col2[e]; src = row2[e]; w = ew2[e]; }
      else if (g < T3) { int e = g - T2; bin = B2 + cl1[e]; src = e; }
      else             { int e = g - T3; bin = B3 + cl2[e]; src = e; }
    }
    bins[j] = bin; srcs[j] = src; wv[j] = w;
    rk[j] = (bin >= 0) ? atomicAdd(&h[bucket_of(bin)], 1) : 0;
  }
  __syncthreads();
  for (int i = threadIdx.x; i < NBK; i += 256) {
    int c = h[i];
    gbase[i] = c ? atomicAdd(&cursor[i], c) : 0;
  }
  __syncthreads();
#pragma unroll
  for (int j = 0; j < 16; j++) {
    if (bins[j] >= 0) {
      int slot = gbase[bucket_of(bins[j])] + rk[j];
      part[slot] = make_int4(bins[j], srcs[j], __float_as_int(wv[j]), 0);
    }
  }
}

// ---------------- P4: per-bucket bin sort -> startsg, rowS, ewSm ----------------
__global__ __launch_bounds__(256) void p4_kernel(const int* __restrict__ bucketStart,
                                                 const int4* __restrict__ part,
                                                 int* __restrict__ startsg,
                                                 int* __restrict__ rowS,
                                                 float* __restrict__ ewSm) {
  int b = blockIdx.x;
  int binLo, width;
  if (b < Q0)      { binLo = b << 7;                 width = 128; if (binLo + width > B0) width = B0 - binLo; }
  else if (b < Q1) { binLo = B0 + ((b - Q0) << 3);   width = 8; }
  else if (b < Q2) { binLo = B1 + (b - Q1);          width = 1; }
  else if (b < Q3) { binLo = B2 + ((b - Q2) << 7);   width = 128; if (binLo + width > B3) width = B3 - binLo; }
  else             { binLo = B3 + ((b - Q3) << 4);   width = 16; if (binLo + width > NTOT) width = NTOT - binLo; }
  int base = bucketStart[b], nend = bucketStart[b + 1];
  int t = threadIdx.x;

  if (width == 1) {
    if (t == 0) startsg[binLo] = base;
    bool isEw = (binLo >= B0 && binLo < B2);
    for (int i = base + t; i < nend; i += 256) {
      int4 it = part[i];
      rowS[i] = it.y;
      if (isEw) ewSm[i] = __int_as_float(it.z);
    }
    return;
  }

  __shared__ int h[128];
  __shared__ int cur[128];
  if (t < 128) h[t] = 0;
  __syncthreads();
  for (int i = base + t; i < nend; i += 256) atomicAdd(&h[part[i].x - binLo], 1);
  __syncthreads();
  if (t == 0) {
    int run = 0;
    for (int j = 0; j < width; j++) {
      cur[j] = run;
      startsg[binLo + j] = base + run;
      run += h[j];
    }
  }
  __syncthreads();
  for (int i = base + t; i < nend; i += 256) {
    int4 it = part[i];
    int k = it.x;
    int r = atomicAdd(&cur[k - binLo], 1);
    int dst = base + r;
    rowS[dst] = it.y;
    if (k >= B0 && k < B2) ewSm[dst] = __int_as_float(it.z);
  }
}

// ---------------- dinv + weighted degrees ----------------
__global__ void dinv_kernel(const int* __restrict__ startsg, const float* __restrict__ ewSm,
                            float* __restrict__ d0, float* __restrict__ d1w,
                            float* __restrict__ d1o, float* __restrict__ d2) {
  int t = blockIdx.x * 256 + threadIdx.x;
  if (t < kN0) {
    int c = startsg[t + 1] - startsg[t];
    d0[t] = c > 0 ? rsqrtf((float)c) : 0.f;
  }
  int wid = t >> 6, lane = t & 63;
  if (wid < kC1) {
    int s = startsg[B0 + wid], e = startsg[B0 + wid + 1];
    float a = 0.f;
    for (int k = s + lane; k < e; k += 64) a += ewSm[k];
    for (int o = 32; o > 0; o >>= 1) a += __shfl_down(a, o);
    if (lane == 0) {
      d1w[wid] = a > 0.f ? rsqrtf(a) : 0.f;
      int c = e - s;
      d1o[wid] = c > 0 ? rsqrtf((float)c) : 0.f;
    }
  } else if (wid < kC1 + kC2) {
    int w2 = wid - kC1;
    int s = startsg[B1 + w2], e = startsg[B1 + w2 + 1];
    float a = 0.f;
    for (int k = s + lane; k < e; k += 64) a += ewSm[k];
    for (int o = 32; o > 0; o >>= 1) a += __shfl_down(a, o);
    if (lane == 0) d2[w2] = a > 0.f ? rsqrtf(a) : 0.f;
  }
}

// ---------------- per-edge weight precompute (seg1/seg2 only) ----------------
__global__ void wprep_kernel(const int* __restrict__ rowS, const float* __restrict__ ewSm,
                             const float* __restrict__ d1w, const float* __restrict__ d2,
                             int E0, int E1, int E2,
                             float* __restrict__ wAll) {
  int e = blockIdx.x * 256 + threadIdx.x + E0;
  int tot = E0 + E1 + E2;
  if (e >= tot) return;
  int r = rowS[e];
  if (e < E0 + E1) {
    wAll[e] = d1w[r] * ewSm[e];
  } else {
    wAll[e] = d2[r] * ewSm[e];
  }
}

// ---------------- scalar GEMM (small N / f32 out / pair-packed bf16 out) ----------
__global__ __launch_bounds__(256) void matmul_kernel(const float* __restrict__ X,
                                                     const float* __restrict__ Xadd,
                                                     const int* __restrict__ cl,
                                                     const float* __restrict__ W,
                                                     const float* __restrict__ bias,
                                                     const float* __restrict__ rowScale,
                                                     float* __restrict__ Y,
                                                     unsigned int* __restrict__ Ybf, int N) {
  __shared__ float Ws[64 * 128];
  __shared__ float Xs[32 * 128];
  int t = threadIdx.x;
  int rbase = blockIdx.x * 32;
  const float4* X4 = (const float4*)X;
  float4* Xs4 = (float4*)Xs;
#pragma unroll
  for (int i = 0; i < 4; i++) {
    int idx = t + 256 * i;
    int fr = idx >> 5, fc = idx & 31;
    int row = rbase + fr; if (row >= N) row = N - 1;
    float4 v = X4[(size_t)row * 32 + fc];
    if (Xadd) {
      int c = cl[row];
      float4 u = ((const float4*)Xadd)[(size_t)c * 32 + fc];
      v.x += u.x; v.y += u.y; v.z += u.z; v.w += u.w;
    }
    Xs4[idx] = v;
  }
  float acc[4][4];
#pragma unroll
  for (int r = 0; r < 4; r++)
#pragma unroll
    for (int cc = 0; cc < 4; cc++) acc[r][cc] = 0.f;
  int c0 = (t & 31) * 4;
  int rl = (t >> 5) * 4;
  const float4* W4 = (const float4*)W;
  float4* Ws4 = (float4*)Ws;
  for (int half = 0; half < 2; half++) {
    __syncthreads();
#pragma unroll
    for (int i = 0; i < 8; i++) {
      int idx = t + 256 * i;
      Ws4[idx] = W4[half * 2048 + idx];
    }
    __syncthreads();
#pragma unroll 4
    for (int k = 0; k < 64; k++) {
      float4 w4 = *(const float4*)(Ws + k * 128 + c0);
      float xv[4];
#pragma unroll
      for (int r = 0; r < 4; r++) xv[r] = Xs[(rl + r) * 128 + half * 64 + k];
#pragma unroll
      for (int r = 0; r < 4; r++) {
        acc[r][0] = fmaf(xv[r], w4.x, acc[r][0]);
        acc[r][1] = fmaf(xv[r], w4.y, acc[r][1]);
        acc[r][2] = fmaf(xv[r], w4.z, acc[r][2]);
        acc[r][3] = fmaf(xv[r], w4.w, acc[r][3]);
      }
    }
  }
  float4 b4 = make_float4(0.f, 0.f, 0.f, 0.f);
  if (bias) b4 = *(const float4*)(bias + c0);
#pragma unroll
  for (int r = 0; r < 4; r++) {
    int row = rbase + rl + r;
    if (row < N) {
      float sc = rowScale ? rowScale[row] : 1.f;
      float4 o;
      o.x = (acc[r][0] + b4.x) * sc; o.y = (acc[r][1] + b4.y) * sc;
      o.z = (acc[r][2] + b4.z) * sc; o.w = (acc[r][3] + b4.w) * sc;
      if (Ybf) {
        unsigned int pk0 = f2_to_bf2(o.x, o.y);
        unsigned int pk1 = f2_to_bf2(o.z, o.w);
        *(uint2*)(Ybf + (size_t)row * 64 + (c0 >> 1)) = make_uint2(pk0, pk1);
      } else {
        *(float4*)(Y + (size_t)row * 128 + c0) = o;
      }
    }
  }
}

// ---------------- MFMA GEMM: Ybf = split-pack bf16 of rowScale[row] * ((X [+ Xadd[cl]]) @ W [+ bias]) ----
__global__ __launch_bounds__(256, 2) void mfma_gemm_kernel(
    const float* __restrict__ X, const float* __restrict__ Xadd,
    const int* __restrict__ cl, const float* __restrict__ W,
    const float* __restrict__ bias, const float* __restrict__ rowScale,
    unsigned int* __restrict__ Ybf, int N) {
  __shared__ unsigned int Bt[128 * 64];  // Bt[n][k] bf16 pairs, XOR-swizzled
  int t = threadIdx.x;
  {
    int n = t & 127, kh = t >> 7;
#pragma unroll
    for (int k = kh * 64; k < kh * 64 + 64; k += 2) {
      float a = W[(size_t)k * 128 + n];
      float b = W[(size_t)(k + 1) * 128 + n];
      unsigned int pk = (unsigned int)f2bf(a) | ((unsigned int)f2bf(b) << 16);
      unsigned int byteoff = ((unsigned int)(n * 256 + k * 2)) ^ (((unsigned int)n & 7u) << 4);
      *(unsigned int*)((char*)Bt + byteoff) = pk;
    }
  }
  __syncthreads();
  int wv = t >> 6, lane = t & 63;
  int g = lane >> 4, mrow = lane & 15;
  int rbase = blockIdx.x * 128 + wv * 32;
  bf16x8 ahi[2][4], alo[2][4];
#pragma unroll
  for (int mt = 0; mt < 2; mt++) {
    int row = rbase + mt * 16 + mrow;
    int rc = row < N ? row : N - 1;
    const float4* Xr = (const float4*)(X + (size_t)rc * 128);
    const float4* Ar = Xadd ? (const float4*)(Xadd + (size_t)cl[rc] * 128) : nullptr;
#pragma unroll
    for (int ks = 0; ks < 4; ks++) {
      int c4 = ks * 8 + g * 2;  // float4 index; col = ks*32 + g*8
      float4 v0 = Xr[c4], v1 = Xr[c4 + 1];
      if (Ar) {
        float4 u0 = Ar[c4], u1 = Ar[c4 + 1];
        v0.x += u0.x; v0.y += u0.y; v0.z += u0.z; v0.w += u0.w;
        v1.x += u1.x; v1.y += u1.y; v1.z += u1.z; v1.w += u1.w;
      }
      float vv[8] = {v0.x, v0.y, v0.z, v0.w, v1.x, v1.y, v1.z, v1.w};
      bf16x8 h, l;
#pragma unroll
      for (int j = 0; j < 8; j++) {
        unsigned short hb = f2bf(vv[j]);
        h[j] = (short)hb;
        l[j] = (short)f2bf(vv[j] - bf2f(hb));
      }
      ahi[mt][ks] = h; alo[mt][ks] = l;
    }
  }
  f32x4 acc[2][8];
#pragma unroll
  for (int mt = 0; mt < 2; mt++)
#pragma unroll
    for (int nt = 0; nt < 8; nt++) acc[mt][nt] = (f32x4){0.f, 0.f, 0.f, 0.f};
#pragma unroll
  for (int ks = 0; ks < 4; ks++) {
#pragma unroll
    for (int nt = 0; nt < 8; nt++) {
      int n = nt * 16 + mrow;
      unsigned int byteoff =
          ((unsigned int)(n * 256 + ks * 64 + g * 16)) ^ (((unsigned int)n & 7u) << 4);
      bf16x8 b = *(const bf16x8*)((const char*)Bt + byteoff);
      acc[0][nt] = __builtin_amdgcn_mfma_f32_16x16x32_bf16(ahi[0][ks], b, acc[0][nt], 0, 0, 0);
      acc[1][nt] = __builtin_amdgcn_mfma_f32_16x16x32_bf16(ahi[1][ks], b, acc[1][nt], 0, 0, 0);
      acc[0][nt] = __builtin_amdgcn_mfma_f32_16x16x32_bf16(alo[0][ks], b, acc[0][nt], 0, 0, 0);
      acc[1][nt] = __builtin_amdgcn_mfma_f32_16x16x32_bf16(alo[1][ks], b, acc[1][nt], 0, 0, 0);
    }
  }
#pragma unroll
  for (int mt = 0; mt < 2; mt++) {
#pragma unroll
    for (int r = 0; r < 4; r++) {
      int row = rbase + mt * 16 + g * 4 + r;
      if (row < N) {
        float sc = rowScale ? rowScale[row] : 1.f;
#pragma unroll
        for (int nt = 0; nt < 4; nt++) {
          int c = nt * 16 + mrow;
          float lo = (acc[mt][nt][r] + (bias ? bias[c] : 0.f)) * sc;
          float hi = (acc[mt][nt + 4][r] + (bias ? bias[c + 64] : 0.f)) * sc;
          Ybf[(size_t)row * 64 + c] = (unsigned int)f2bf(lo) | ((unsigned int)f2bf(hi) << 16);
        }
      }
    }
  }
}

// ---------------- CSR aggregation, wave per node, SPLIT-packed bf16, UNWEIGHTED ----
// Quad-edge pairing: 16 lanes per edge row, 4 edges per load instruction.
// Lane = 16*g + hl; g = edge slot (0..3), hl = feature quarter (0..15).
// Each lane loads uint4 (4 words = 8 features: 4hl..4hl+3 and 64+4hl..64+4hl+3).
// Reduce over edge slots via shfl_xor(16,32); groups 0/1 store float4 lo/hi.
__global__ __launch_bounds__(256) void agg_kernel(const unsigned int* __restrict__ Hf,
                                                  float* __restrict__ out,
                                                  const int* __restrict__ starts,
                                                  const int* __restrict__ rowS,
                                                  const float* __restrict__ dinv,
                                                  const float* __restrict__ bias,
                                                  int C, int relu) {
  int wid = (blockIdx.x * blockDim.x + threadIdx.x) >> 6;
  int lane = threadIdx.x & 63;
  if (wid >= C) return;
  int g = lane >> 4, hl = lane & 15;
  const uint4* Hf4 = (const uint4*)Hf;
  int s = starts[wid], e = starts[wid + 1];
  float dc = dinv[wid];
  float a0 = 0.f, a1 = 0.f, a2 = 0.f, a3 = 0.f;
  float b0 = 0.f, b1 = 0.f, b2 = 0.f, b3 = 0.f;
  for (int base = s; base < e; base += 64) {
    int n = e - base; if (n > 64) n = 64;
    int r = rowS[base + (lane < n ? lane : 0)];
    for (int j = 0; j < n; j += 16) {
#pragma unroll
      for (int u = 0; u < 4; u++) {
        if (j + u * 4 >= n) break;  // wave-uniform: all 4 slots past end
        int eidx = j + u * 4 + g;
        bool v = eidx < n;
        int rr = __shfl(r, v ? eidx : 0);
        uint4 pv = Hf4[(size_t)rr * 16 + hl];
        if (!v) { pv.x = 0u; pv.y = 0u; pv.z = 0u; pv.w = 0u; }
        a0 += __uint_as_float(pv.x << 16);
        b0 += __uint_as_float(pv.x & 0xffff0000u);
        a1 += __uint_as_float(pv.y << 16);
        b1 += __uint_as_float(pv.y & 0xffff0000u);
        a2 += __uint_as_float(pv.z << 16);
        b2 += __uint_as_float(pv.z & 0xffff0000u);
        a3 += __uint_as_float(pv.w << 16);
        b3 += __uint_as_float(pv.w & 0xffff0000u);
      }
    }
  }
  a0 += __shfl_xor(a0, 16); a0 += __shfl_xor(a0, 32);
  a1 += __shfl_xor(a1, 16); a1 += __shfl_xor(a1, 32);
  a2 += __shfl_xor(a2, 16); a2 += __shfl_xor(a2, 32);
  a3 += __shfl_xor(a3, 16); a3 += __shfl_xor(a3, 32);
  b0 += __shfl_xor(b0, 16); b0 += __shfl_xor(b0, 32);
  b1 += __shfl_xor(b1, 16); b1 += __shfl_xor(b1, 32);
  b2 += __shfl_xor(b2, 16); b2 += __shfl_xor(b2, 32);
  b3 += __shfl_xor(b3, 16); b3 += __shfl_xor(b3, 32);
  if (g < 2) {
    float s0 = g ? b0 : a0;
    float s1 = g ? b1 : a1;
    float s2 = g ? b2 : a2;
    float s3 = g ? b3 : a3;
    int c0 = g * 64 + hl * 4;
    float4 bb = *(const float4*)(bias + c0);
    float4 o;
    o.x = s0 * dc + bb.x;
    o.y = s1 * dc + bb.y;
    o.z = s2 * dc + bb.z;
    o.w = s3 * dc + bb.w;
    if (relu) {
      o.x = fmaxf(o.x, 0.f); o.y = fmaxf(o.y, 0.f);
      o.z = fmaxf(o.z, 0.f); o.w = fmaxf(o.w, 0.f);
    }
    *(float4*)(out + (size_t)wid * 128 + c0) = o;
  }
}

// ---------------- CSR aggregation, BLOCK per node, PAIR-packed bf16, weighted ------
__global__ __launch_bounds__(256) void aggb_kernel(const unsigned int* __restrict__ Hf,
                                                   float* __restrict__ out,
                                                   const int* __restrict__ starts,
                                                   const int* __restrict__ rowS,
                                                   const float* __restrict__ wS,
                                                   const float* __restrict__ dinv,
                                                   const float* __restrict__ bias,
                                                   int C, int relu) {
  int node = blockIdx.x;
  if (node >= C) return;
  int wv = threadIdx.x >> 6, lane = threadIdx.x & 63;
  int s = starts[node], e = starts[node + 1];
  float ax[4] = {0.f, 0.f, 0.f, 0.f}, ay[4] = {0.f, 0.f, 0.f, 0.f};
  for (int base = s + wv * 64; base < e; base += 256) {
    int n = e - base; if (n > 64) n = 64;
    int moff = base + (lane < n ? lane : 0);
    int r = rowS[moff];
    float w = wS[moff];
    int j = 0;
    for (; j + 15 < n; j += 16) {
#pragma unroll
      for (int u = 0; u < 16; u++) {
        int rr = __shfl(r, j + u);
        float ww = __shfl(w, j + u);
        unsigned int pv = Hf[(size_t)rr * 64 + lane];
        ax[u & 3] = fmaf(ww, __uint_as_float(pv << 16), ax[u & 3]);
        ay[u & 3] = fmaf(ww, __uint_as_float(pv & 0xffff0000u), ay[u & 3]);
      }
    }
    for (; j < n; j++) {
      int rr = __shfl(r, j);
      float ww = __shfl(w, j);
      unsigned int pv = Hf[(size_t)rr * 64 + lane];
      ax[0] = fmaf(ww, __uint_as_float(pv << 16), ax[0]);
      ay[0] = fmaf(ww, __uint_as_float(pv & 0xffff0000u), ay[0]);
    }
  }
  __shared__ float shx[256], shy[256];
  shx[threadIdx.x] = ax[0] + ax[1] + ax[2] + ax[3];
  shy[threadIdx.x] = ay[0] + ay[1] + ay[2] + ay[3];
  __syncthreads();
  if (threadIdx.x < 64) {
    float sx = shx[lane] + shx[lane + 64] + shx[lane + 128] + shx[lane + 192];
    float sy = shy[lane] + shy[lane + 64] + shy[lane + 128] + shy[lane + 192];
    float dc = dinv[node];
    float ox = sx * dc + bias[lane * 2];
    float oy = sy * dc + bias[lane * 2 + 1];
    if (relu) { ox = fmaxf(ox, 0.f); oy = fmaxf(oy, 0.f); }
    *(float2*)(out + (size_t)node * 128 + lane * 2) = make_float2(ox, oy);
  }
}

// ---------------- CSR aggregation, BLOCK per node, PAIR-packed bf16, UNWEIGHTED ----
__global__ __launch_bounds__(256) void aggb1_kernel(const unsigned int* __restrict__ Hf,
                                                    float* __restrict__ out,
                                                    const int* __restrict__ starts,
                                                    const int* __restrict__ rowS,
                                                    const float* __restrict__ dinv,
                                                    const float* __restrict__ bias,
                                                    int C, int relu) {
  int node = blockIdx.x;
  if (node >= C) return;
  int wv = threadIdx.x >> 6, lane = threadIdx.x & 63;
  int s = starts[node], e = starts[node + 1];
  float ax[4] = {0.f, 0.f, 0.f, 0.f}, ay[4] = {0.f, 0.f, 0.f, 0.f};
  for (int base = s + wv * 64; base < e; base += 256) {
    int n = e - base; if (n > 64) n = 64;
    int r = rowS[base + (lane < n ? lane : 0)];
    int j = 0;
    for (; j + 15 < n; j += 16) {
#pragma unroll
      for (int u = 0; u < 16; u++) {
        int rr = __shfl(r, j + u);
        unsigned int pv = Hf[(size_t)rr * 64 + lane];
        ax[u & 3] += __uint_as_float(pv << 16);
        ay[u & 3] += __uint_as_float(pv & 0xffff0000u);
      }
    }
    for (; j < n; j++) {
      int rr = __shfl(r, j);
      unsigned int pv = Hf[(size_t)rr * 64 + lane];
      ax[0] += __uint_as_float(pv << 16);
      ay[0] += __uint_as_float(pv & 0xffff0000u);
    }
  }
  __shared__ float shx[256], shy[256];
  shx[threadIdx.x] = ax[0] + ax[1] + ax[2] + ax[3];
  shy[threadIdx.x] = ay[0] + ay[1] + ay[2] + ay[3];
  __syncthreads();
  if (threadIdx.x < 64) {
    float sx = shx[lane] + shx[lane + 64] + shx[lane + 128] + shx[lane + 192];
    float sy = shy[lane] + shy[lane + 64] + shy[lane + 128] + shy[lane + 192];
    float dc = dinv[node];
    float ox = sx * dc + bias[lane * 2];
    float oy = sy * dc + bias[lane * 2 + 1];
    if (relu) { ox = fmaxf(ox, 0.f); oy = fmaxf(oy, 0.f); }
    *(float2*)(out + (size_t)node * 128 + lane * 2) = make_float2(ox, oy);
  }
}

// ---------------- seg_mean pooling (unrolled x8, f32 src) ----------------
__global__ __launch_bounds__(256) void pool_kernel(const float* __restrict__ src,
                                                   float* __restrict__ out,
                                                   const int* __restrict__ starts,
                                                   const int* __restrict__ rowS, int C) {
  int wid = (blockIdx.x * blockDim.x + threadIdx.x) >> 6;
  int lane = threadIdx.x & 63;
  if (wid >= C) return;
  int s = starts[wid], e = starts[wid + 1];
  float ax0 = 0.f, ay0 = 0.f, ax1 = 0.f, ay1 = 0.f;
  int m = s;
  for (; m + 7 < e; m += 8) {
    int idx[8];
#pragma unroll
    for (int u = 0; u < 8; u++) idx[u] = rowS[m + u];
#pragma unroll
    for (int u = 0; u < 8; u++) {
      float2 v = *(const float2*)(src + (size_t)idx[u] * 128 + lane * 2);
      if (u & 1) { ax1 += v.x; ay1 += v.y; } else { ax0 += v.x; ay0 += v.y; }
    }
  }
  for (; m < e; m++) {
    int id = rowS[m];
    const float2 v = *(const float2*)(src + (size_t)id * 128 + lane * 2);
    ax0 += v.x; ay0 += v.y;
  }
  float inv = (e > s) ? 1.f / (float)(e - s) : 0.f;
  *(float2*)(out + (size_t)wid * 128 + lane * 2) =
      make_float2((ax0 + ax1) * inv, (ay0 + ay1) * inv);
}

// ---------------- host ----------------

extern "C" void kernel_launch(void* const* d_in, const int* in_sizes, int n_in,
                              void* d_out, int out_size, void* d_ws, size_t ws_size,
                              hipStream_t stream) {
  const float* x     = (const float*)d_in[0];
  const float* W_pre = (const float*)d_in[1];
  const float* b_pre = (const float*)d_in[2];
  const float* W_u0  = (const float*)d_in[3];
  const float* b_u0  = (const float*)d_in[4];
  const float* W_u1  = (const float*)d_in[5];
  const float* b_u1  = (const float*)d_in[6];
  const float* W_u2  = (const float*)d_in[7];
  const float* b_u2  = (const float*)d_in[8];
  const float* W_d0  = (const float*)d_in[9];
  const float* b_d0  = (const float*)d_in[10];
  const float* W_d1  = (const float*)d_in[11];
  const float* b_d1  = (const float*)d_in[12];
  const int* row0 = (const int*)d_in[13];
  const int* col0 = (const int*)d_in[14];
  const int* row1 = (const int*)d_in[16];
  const int* col1 = (const int*)d_in[17];
  const float* ew1 = (const float*)d_in[18];
  const int* row2 = (const int*)d_in[19];
  const int* col2 = (const int*)d_in[20];
  const float* ew2 = (const float*)d_in[21];
  const int* cluster1 = (const int*)d_in[22];
  const int* cluster2 = (const int*)d_in[23];
  int E0 = in_sizes[13], E1 = in_sizes[16], E2 = in_sizes[19];
  float* out = (float*)d_out;
  int Ttot = E0 + E1 + E2 + kN0 + kC1;
  int Etot = E0 + E1 + E2;

  char* basep = (char*)d_ws;
  size_t off = 0;
  auto alloc = [&](size_t bytes) -> char* {
    char* p = basep + off;
    off = (off + bytes + 255) & ~(size_t)255;
    return p;
  };
  // zero-init: bucketCnt only
  int* bucketCnt = (int*)alloc((size_t)NBK * 4);
  size_t zero_bytes = off;
  // persistent
  int* bucketStart = (int*)alloc((size_t)(NBK + 1) * 4);
  int* cursor      = (int*)alloc((size_t)NBK * 4);
  int* startsg     = (int*)alloc((size_t)(NTOT + 1) * 4);
  int* rowS  = (int*)alloc((size_t)Ttot * 4);
  float* ewS = (float*)alloc((size_t)(E1 + E2) * 4);
  float* ewSm = ewS - E0;
  float* dinv0  = (float*)alloc((size_t)kN0 * 4);
  float* dinv1w = (float*)alloc((size_t)kC1 * 4);
  float* dinv1o = (float*)alloc((size_t)kC1 * 4);
  float* dinv2  = (float*)alloc((size_t)kC2 * 4);
  // --- overlay: part (dead after p4) aliases everything written after p4 ---
  size_t watermark = off;
  int4* part = (int4*)alloc((size_t)Ttot * 16);
  off = watermark;
  float* wAll = (float*)alloc((size_t)Etot * 4);
  float* Wf   = (float*)alloc((size_t)128 * 128 * 4);
  float* bfv  = (float*)alloc((size_t)128 * 4);
  float* A    = (float*)alloc((size_t)kN0 * HH * 4);
  float* s1a  = (float*)alloc((size_t)kC1 * HH * 4);
  float* s1b  = (float*)alloc((size_t)kC1 * HH * 4);
  float* s2a  = (float*)alloc((size_t)kC2 * HH * 4);
  unsigned int* s1bb = (unsigned int*)alloc((size_t)kC1 * 64 * 4);
  unsigned int* s2bb = (unsigned int*)alloc((size_t)kC2 * 64 * 4);
  unsigned int* s1cb = (unsigned int*)alloc((size_t)kC1 * 64 * 4);
  unsigned int* tb   = (unsigned int*)alloc((size_t)kN0 * 64 * 4);
  unsigned int* t0   = (unsigned int*)d_out;  // bf16 scratch in d_out (dead before final write)

  hipMemsetAsync(d_ws, 0, zero_bytes, stream);

  auto cdiv = [](int a, int b) { return (a + b - 1) / b; };

  // CSR build
  p1_kernel<<<256, 256, 0, stream>>>(col0, col1, col2, cluster1, cluster2, E0, E1, E2, bucketCnt);
  p2_kernel<<<1, 1024, 0, stream>>>(bucketCnt, bucketStart, cursor, startsg, Ttot);
  p3_kernel<<<cdiv(Ttot, 4096), 256, 0, stream>>>(col0, col1, col2, cluster1, cluster2,
                                                  row0, row1, row2, ew1, ew2, E0, E1, E2,
                                                  cursor, part);
  p4_kernel<<<NBK, 256, 0, stream>>>(bucketStart, part, startsg, rowS, ewSm);
  dinv_kernel<<<cdiv((kC1 + kC2) * 64, 256), 256, 0, stream>>>(startsg, ewSm, dinv0, dinv1w,
                                                               dinv1o, dinv2);
  wprep_kernel<<<cdiv(E1 + E2, 256), 256, 0, stream>>>(rowS, ewSm, dinv1w, dinv2,
                                                       E0, E1, E2, wAll);

  // Fused pre+u0 weights: Wf = W_pre @ W_u0 (128x128), bfv = b_pre @ W_u0 (1x128)
  matmul_kernel<<<cdiv(128, 32), 256, 0, stream>>>(W_pre, nullptr, nullptr, W_u0, nullptr,
                                                   nullptr, Wf, nullptr, 128);
  matmul_kernel<<<1, 256, 0, stream>>>(b_pre, nullptr, nullptr, W_u0, nullptr,
                                       nullptr, bfv, nullptr, 1);
  // t0 = dinv0[row] * (x@Wf + bfv) -> bf16 split-packed (d_out scratch)
  mfma_gemm_kernel<<<cdiv(kN0, 128), 256, 0, stream>>>(x, nullptr, nullptr, Wf, bfv, dinv0,
                                                       t0, kN0);
  // x0 = relu(agg0(t0) + b_u0) -> A   (unweighted; dinv0 folded into table)
  agg_kernel<<<cdiv(kN0, 4), 256, 0, stream>>>(t0, A, startsg, rowS, dinv0, b_u0, kN0, 1);
  // x1m = seg_mean(x0, cluster1) -> s1a
  pool_kernel<<<cdiv(kC1, 4), 256, 0, stream>>>(A, s1a, startsg + B2, rowS, kC1);
  // t1 = x1m@W_u1 -> bf16 s1bb (pair-packed)
  matmul_kernel<<<cdiv(kC1, 32), 256, 0, stream>>>(s1a, nullptr, nullptr, W_u1, nullptr,
                                                   nullptr, nullptr, s1bb, kC1);
  // x1 = relu(agg1_w(t1) + b_u1) -> s1a
  aggb_kernel<<<kC1, 256, 0, stream>>>(s1bb, s1a, startsg + B0, rowS, wAll, dinv1w, b_u1, kC1, 1);
  // x2m = seg_mean(x1, cluster2) -> s2a
  pool_kernel<<<cdiv(kC2, 4), 256, 0, stream>>>(s1a, s2a, startsg + B3, rowS, kC2);
  // t2 = x2m@W_u2 -> bf16 s2bb
  matmul_kernel<<<cdiv(kC2, 32), 256, 0, stream>>>(s2a, nullptr, nullptr, W_u2, nullptr,
                                                   nullptr, nullptr, s2bb, kC2);
  // x2 = relu(agg2_w(t2) + b_u2) -> s2a
  aggb_kernel<<<kC2, 256, 0, stream>>>(s2bb, s2a, startsg + B1, rowS, wAll, dinv2, b_u2, kC2, 1);
  // fused: d1o[row] * ((x1 + x2[cluster2]) @ W_d1) -> bf16 s1cb
  matmul_kernel<<<cdiv(kC1, 32), 256, 0, stream>>>(s1a, s2a, cluster2, W_d1, nullptr,
                                                   dinv1o, nullptr, s1cb, kC1);
  // y1 = relu(agg1_ones(s1cb) + b_d1) -> s1b   (unweighted; d1o folded into table)
  aggb1_kernel<<<kC1, 256, 0, stream>>>(s1cb, s1b, startsg + B0, rowS, dinv1o, b_d1, kC1, 1);
  // fused addgather: tb = dinv0[row] * ((x0 + y1[cluster1]) @ W_d0) -> bf16 split-packed
  mfma_gemm_kernel<<<cdiv(kN0, 128), 256, 0, stream>>>(A, s1b, cluster1, W_d0, nullptr, dinv0,
                                                       tb, kN0);
  // final: out = agg0(tb) + b_d0 (no relu; unweighted)
  agg_kernel<<<cdiv(kN0, 4), 256, 0, stream>>>(tb, out, startsg, rowS, dinv0, b_d0, kN0, 0);
}

// Round 8
// 634.628 us; speedup vs baseline: 1.0430x; 1.0430x over previous
//
#include <hip/hip_runtime.h>

#define HH 128
static constexpr int kN0 = 100000;
static constexpr int kC1 = 10000;
static constexpr int kC2 = 1000;

// Contiguous bin layout for the 5 CSR segments:
// [bins0 (kN0) | bins1 (kC1) | bins2 (kC2) | binsP1 (kC1) | binsP2 (kC2)]
static constexpr int B0 = kN0;              // 100000
static constexpr int B1 = B0 + kC1;         // 110000
static constexpr int B2 = B1 + kC2;         // 111000
static constexpr int B3 = B2 + kC1;         // 121000
static constexpr int NTOT = B3 + kC2;       // 122000

// Variable-width buckets, ~uniform ITEM count:
static constexpr int NB0 = (kN0 + 127) / 128;   // 782
static constexpr int NB1 = (kC1 + 7) / 8;       // 1250
static constexpr int NB2 = kC2;                 // 1000
static constexpr int NBP1 = (kC1 + 127) / 128;  // 79
static constexpr int NBP2 = (kC2 + 15) / 16;    // 63
static constexpr int Q0 = NB0;                  // 782
static constexpr int Q1 = Q0 + NB1;             // 2032
static constexpr int Q2 = Q1 + NB2;             // 3032
static constexpr int Q3 = Q2 + NBP1;            // 3111
static constexpr int NBK = Q3 + NBP2;           // 3174

__device__ __forceinline__ int bucket_of(int bin) {
  if (bin < B0) return bin >> 7;
  if (bin < B1) return Q0 + ((bin - B0) >> 3);
  if (bin < B2) return Q1 + (bin - B1);
  if (bin < B3) return Q2 + ((bin - B2) >> 7);
  return Q3 + ((bin - B3) >> 4);
}

// bf16x2 helpers
__device__ __forceinline__ unsigned int f2_to_bf2(float a, float b) {
  unsigned int ua = __float_as_uint(a);
  unsigned int ub = __float_as_uint(b);
  ua = (ua + 0x7fffu + ((ua >> 16) & 1u)) >> 16;
  ub = (ub + 0x7fffu + ((ub >> 16) & 1u)) & 0xffff0000u;
  return ua | ub;
}
__device__ __forceinline__ unsigned short f2bf(float f) {
  unsigned int u = __float_as_uint(f);
  u = (u + 0x7fffu + ((u >> 16) & 1u)) >> 16;
  return (unsigned short)u;
}
__device__ __forceinline__ float bf2f(unsigned short s) {
  return __uint_as_float(((unsigned int)s) << 16);
}

using bf16x8 = __attribute__((ext_vector_type(8))) short;
using f32x4 = __attribute__((ext_vector_type(4))) float;

// ---------------- P1: bucket histogram ----------------
__global__ __launch_bounds__(256) void p1_kernel(const int* __restrict__ col0,
                                                 const int* __restrict__ col1,
                                                 const int* __restrict__ col2,
                                                 const int* __restrict__ cl1,
                                                 const int* __restrict__ cl2,
                                                 int E0, int E1, int E2,
                                                 int* __restrict__ bucketCnt) {
  __shared__ int h[NBK];
  for (int i = threadIdx.x; i < NBK; i += 256) h[i] = 0;
  __syncthreads();
  int T0 = E0, T1 = T0 + E1, T2 = T1 + E2, T3 = T2 + kN0, T4 = T3 + kC1;
  for (int g = blockIdx.x * 256 + threadIdx.x; g < T4; g += gridDim.x * 256) {
    int bin;
    if (g < T0)      bin = col0[g];
    else if (g < T1) bin = B0 + col1[g - T0];
    else if (g < T2) bin = B1 + col2[g - T1];
    else if (g < T3) bin = B2 + cl1[g - T2];
    else             bin = B3 + cl2[g - T3];
    atomicAdd(&h[bucket_of(bin)], 1);
  }
  __syncthreads();
  for (int i = threadIdx.x; i < NBK; i += 256) {
    int c = h[i];
    if (c) atomicAdd(&bucketCnt[i], c);
  }
}

// ---------------- P2: scan bucket counts ----------------
__global__ __launch_bounds__(1024) void p2_kernel(const int* __restrict__ bucketCnt,
                                                  int* __restrict__ bucketStart,
                                                  int* __restrict__ cursor,
                                                  int* __restrict__ startsg, int T) {
  int t = threadIdx.x;
  int v[4]; int s = 0;
#pragma unroll
  for (int j = 0; j < 4; j++) {
    int i = t * 4 + j;
    v[j] = (i < NBK) ? bucketCnt[i] : 0;
    s += v[j];
  }
  int lane = t & 63, w = t >> 6;
  int incl = s;
  for (int o = 1; o < 64; o <<= 1) { int u = __shfl_up(incl, o); if (lane >= o) incl += u; }
  __shared__ int wt[16];
  if (lane == 63) wt[w] = incl;
  __syncthreads();
  if (t == 0) { int run = 0; for (int i = 0; i < 16; i++) { int c = wt[i]; wt[i] = run; run += c; } }
  __syncthreads();
  int ex = wt[w] + incl - s;
#pragma unroll
  for (int j = 0; j < 4; j++) {
    int i = t * 4 + j;
    if (i < NBK) { bucketStart[i] = ex; cursor[i] = ex; }
    ex += v[j];
  }
  if (t == 0) { bucketStart[NBK] = T; startsg[NTOT] = T; }
}

// ---------------- P3: partition into buckets (int4 payload, single 16B store) ----
__global__ __launch_bounds__(256) void p3_kernel(const int* __restrict__ col0,
                                                 const int* __restrict__ col1,
                                                 const int* __restrict__ col2,
                                                 const int* __restrict__ cl1,
                                                 const int* __restrict__ cl2,
                                                 const int* __restrict__ row0,
                                                 const int* __restrict__ row1,
                                                 const int* __restrict__ row2,
                                                 const float* __restrict__ ew1,
                                                 const float* __restrict__ ew2,
                                                 int E0, int E1, int E2,
                                                 int* __restrict__ cursor,
                                                 int4* __restrict__ part) {
  __shared__ int h[NBK];
  __shared__ int gbase[NBK];
  for (int i = threadIdx.x; i < NBK; i += 256) h[i] = 0;
  __syncthreads();
  int T0 = E0, T1 = T0 + E1, T2 = T1 + E2, T3 = T2 + kN0, T4 = T3 + kC1;
  int base = blockIdx.x * 4096;
  int bins[16], srcs[16], rk[16];
  float wv[16];
#pragma unroll
  for (int j = 0; j < 16; j++) {
    int g = base + threadIdx.x + j * 256;
    int bin = -1, src = 0; float w = 0.f;
    if (g < T4) {
      if (g < T0) { bin = col0[g]; src = row0[g]; }
      else if (g < T1) { int e = g - T0; bin = B0 + col1[e]; src = row1[e]; w = ew1[e]; }
      else if (g < T2) { int e = g - T1; bin = B1 + col2[e]; src = row2[e]; w = ew2[e]; }
      else if (g < T3) { int e = g - T2; bin = B2 + cl1[e]; src = e; }
      else             { int e = g - T3; bin = B3 + cl2[e]; src = e; }
    }
    bins[j] = bin; srcs[j] = src; wv[j] = w;
    rk[j] = (bin >= 0) ? atomicAdd(&h[bucket_of(bin)], 1) : 0;
  }
  __syncthreads();
  for (int i = threadIdx.x; i < NBK; i += 256) {
    int c = h[i];
    gbase[i] = c ? atomicAdd(&cursor[i], c) : 0;
  }
  __syncthreads();
#pragma unroll
  for (int j = 0; j < 16; j++) {
    if (bins[j] >= 0) {
      int slot = gbase[bucket_of(bins[j])] + rk[j];
      part[slot] = make_int4(bins[j], srcs[j], __float_as_int(wv[j]), 0);
    }
  }
}

// ---------------- P4: per-bucket bin sort -> startsg, rowS, ewSm ----------------
__global__ __launch_bounds__(256) void p4_kernel(const int* __restrict__ bucketStart,
                                                 const int4* __restrict__ part,
                                                 int* __restrict__ startsg,
                                                 int* __restrict__ rowS,
                                                 float* __restrict__ ewSm) {
  int b = blockIdx.x;
  int binLo, width;
  if (b < Q0)      { binLo = b << 7;                 width = 128; if (binLo + width > B0) width = B0 - binLo; }
  else if (b < Q1) { binLo = B0 + ((b - Q0) << 3);   width = 8; }
  else if (b < Q2) { binLo = B1 + (b - Q1);          width = 1; }
  else if (b < Q3) { binLo = B2 + ((b - Q2) << 7);   width = 128; if (binLo + width > B3) width = B3 - binLo; }
  else             { binLo = B3 + ((b - Q3) << 4);   width = 16; if (binLo + width > NTOT) width = NTOT - binLo; }
  int base = bucketStart[b], nend = bucketStart[b + 1];
  int t = threadIdx.x;

  if (width == 1) {
    if (t == 0) startsg[binLo] = base;
    bool isEw = (binLo >= B0 && binLo < B2);
    for (int i = base + t; i < nend; i += 256) {
      int4 it = part[i];
      rowS[i] = it.y;
      if (isEw) ewSm[i] = __int_as_float(it.z);
    }
    return;
  }

  __shared__ int h[128];
  __shared__ int cur[128];
  if (t < 128) h[t] = 0;
  __syncthreads();
  for (int i = base + t; i < nend; i += 256) atomicAdd(&h[part[i].x - binLo], 1);
  __syncthreads();
  if (t == 0) {
    int run = 0;
    for (int j = 0; j < width; j++) {
      cur[j] = run;
      startsg[binLo + j] = base + run;
      run += h[j];
    }
  }
  __syncthreads();
  for (int i = base + t; i < nend; i += 256) {
    int4 it = part[i];
    int k = it.x;
    int r = atomicAdd(&cur[k - binLo], 1);
    int dst = base + r;
    rowS[dst] = it.y;
    if (k >= B0 && k < B2) ewSm[dst] = __int_as_float(it.z);
  }
}

// ---------------- dinv + weighted degrees ----------------
__global__ void dinv_kernel(const int* __restrict__ startsg, const float* __restrict__ ewSm,
                            float* __restrict__ d0, float* __restrict__ d1w,
                            float* __restrict__ d1o, float* __restrict__ d2) {
  int t = blockIdx.x * 256 + threadIdx.x;
  if (t < kN0) {
    int c = startsg[t + 1] - startsg[t];
    d0[t] = c > 0 ? rsqrtf((float)c) : 0.f;
  }
  int wid = t >> 6, lane = t & 63;
  if (wid < kC1) {
    int s = startsg[B0 + wid], e = startsg[B0 + wid + 1];
    float a = 0.f;
    for (int k = s + lane; k < e; k += 64) a += ewSm[k];
    for (int o = 32; o > 0; o >>= 1) a += __shfl_down(a, o);
    if (lane == 0) {
      d1w[wid] = a > 0.f ? rsqrtf(a) : 0.f;
      int c = e - s;
      d1o[wid] = c > 0 ? rsqrtf((float)c) : 0.f;
    }
  } else if (wid < kC1 + kC2) {
    int w2 = wid - kC1;
    int s = startsg[B1 + w2], e = startsg[B1 + w2 + 1];
    float a = 0.f;
    for (int k = s + lane; k < e; k += 64) a += ewSm[k];
    for (int o = 32; o > 0; o >>= 1) a += __shfl_down(a, o);
    if (lane == 0) d2[w2] = a > 0.f ? rsqrtf(a) : 0.f;
  }
}

// ---------------- per-edge weight precompute (seg1/seg2 only) ----------------
__global__ void wprep_kernel(const int* __restrict__ rowS, const float* __restrict__ ewSm,
                             const float* __restrict__ d1w, const float* __restrict__ d2,
                             int E0, int E1, int E2,
                             float* __restrict__ wAll) {
  int e = blockIdx.x * 256 + threadIdx.x + E0;
  int tot = E0 + E1 + E2;
  if (e >= tot) return;
  int r = rowS[e];
  if (e < E0 + E1) {
    wAll[e] = d1w[r] * ewSm[e];
  } else {
    wAll[e] = d2[r] * ewSm[e];
  }
}

// ---------------- scalar GEMM (small N / f32 out / pair-packed bf16 out) ----------
__global__ __launch_bounds__(256) void matmul_kernel(const float* __restrict__ X,
                                                     const float* __restrict__ Xadd,
                                                     const int* __restrict__ cl,
                                                     const float* __restrict__ W,
                                                     const float* __restrict__ bias,
                                                     const float* __restrict__ rowScale,
                                                     float* __restrict__ Y,
                                                     unsigned int* __restrict__ Ybf, int N) {
  __shared__ float Ws[64 * 128];
  __shared__ float Xs[32 * 128];
  int t = threadIdx.x;
  int rbase = blockIdx.x * 32;
  const float4* X4 = (const float4*)X;
  float4* Xs4 = (float4*)Xs;
#pragma unroll
  for (int i = 0; i < 4; i++) {
    int idx = t + 256 * i;
    int fr = idx >> 5, fc = idx & 31;
    int row = rbase + fr; if (row >= N) row = N - 1;
    float4 v = X4[(size_t)row * 32 + fc];
    if (Xadd) {
      int c = cl[row];
      float4 u = ((const float4*)Xadd)[(size_t)c * 32 + fc];
      v.x += u.x; v.y += u.y; v.z += u.z; v.w += u.w;
    }
    Xs4[idx] = v;
  }
  float acc[4][4];
#pragma unroll
  for (int r = 0; r < 4; r++)
#pragma unroll
    for (int cc = 0; cc < 4; cc++) acc[r][cc] = 0.f;
  int c0 = (t & 31) * 4;
  int rl = (t >> 5) * 4;
  const float4* W4 = (const float4*)W;
  float4* Ws4 = (float4*)Ws;
  for (int half = 0; half < 2; half++) {
    __syncthreads();
#pragma unroll
    for (int i = 0; i < 8; i++) {
      int idx = t + 256 * i;
      Ws4[idx] = W4[half * 2048 + idx];
    }
    __syncthreads();
#pragma unroll 4
    for (int k = 0; k < 64; k++) {
      float4 w4 = *(const float4*)(Ws + k * 128 + c0);
      float xv[4];
#pragma unroll
      for (int r = 0; r < 4; r++) xv[r] = Xs[(rl + r) * 128 + half * 64 + k];
#pragma unroll
      for (int r = 0; r < 4; r++) {
        acc[r][0] = fmaf(xv[r], w4.x, acc[r][0]);
        acc[r][1] = fmaf(xv[r], w4.y, acc[r][1]);
        acc[r][2] = fmaf(xv[r], w4.z, acc[r][2]);
        acc[r][3] = fmaf(xv[r], w4.w, acc[r][3]);
      }
    }
  }
  float4 b4 = make_float4(0.f, 0.f, 0.f, 0.f);
  if (bias) b4 = *(const float4*)(bias + c0);
#pragma unroll
  for (int r = 0; r < 4; r++) {
    int row = rbase + rl + r;
    if (row < N) {
      float sc = rowScale ? rowScale[row] : 1.f;
      float4 o;
      o.x = (acc[r][0] + b4.x) * sc; o.y = (acc[r][1] + b4.y) * sc;
      o.z = (acc[r][2] + b4.z) * sc; o.w = (acc[r][3] + b4.w) * sc;
      if (Ybf) {
        unsigned int pk0 = f2_to_bf2(o.x, o.y);
        unsigned int pk1 = f2_to_bf2(o.z, o.w);
        *(uint2*)(Ybf + (size_t)row * 64 + (c0 >> 1)) = make_uint2(pk0, pk1);
      } else {
        *(float4*)(Y + (size_t)row * 128 + c0) = o;
      }
    }
  }
}

// ---------------- MFMA GEMM: Ybf = split-pack bf16 of rowScale[row] * ((X [+ Xadd[cl]]) @ W [+ bias]) ----
__global__ __launch_bounds__(256, 2) void mfma_gemm_kernel(
    const float* __restrict__ X, const float* __restrict__ Xadd,
    const int* __restrict__ cl, const float* __restrict__ W,
    const float* __restrict__ bias, const float* __restrict__ rowScale,
    unsigned int* __restrict__ Ybf, int N) {
  __shared__ unsigned int Bt[128 * 64];  // Bt[n][k] bf16 pairs, XOR-swizzled
  int t = threadIdx.x;
  {
    int n = t & 127, kh = t >> 7;
#pragma unroll
    for (int k = kh * 64; k < kh * 64 + 64; k += 2) {
      float a = W[(size_t)k * 128 + n];
      float b = W[(size_t)(k + 1) * 128 + n];
      unsigned int pk = (unsigned int)f2bf(a) | ((unsigned int)f2bf(b) << 16);
      unsigned int byteoff = ((unsigned int)(n * 256 + k * 2)) ^ (((unsigned int)n & 7u) << 4);
      *(unsigned int*)((char*)Bt + byteoff) = pk;
    }
  }
  __syncthreads();
  int wv = t >> 6, lane = t & 63;
  int g = lane >> 4, mrow = lane & 15;
  int rbase = blockIdx.x * 128 + wv * 32;
  bf16x8 ahi[2][4], alo[2][4];
#pragma unroll
  for (int mt = 0; mt < 2; mt++) {
    int row = rbase + mt * 16 + mrow;
    int rc = row < N ? row : N - 1;
    const float4* Xr = (const float4*)(X + (size_t)rc * 128);
    const float4* Ar = Xadd ? (const float4*)(Xadd + (size_t)cl[rc] * 128) : nullptr;
#pragma unroll
    for (int ks = 0; ks < 4; ks++) {
      int c4 = ks * 8 + g * 2;  // float4 index; col = ks*32 + g*8
      float4 v0 = Xr[c4], v1 = Xr[c4 + 1];
      if (Ar) {
        float4 u0 = Ar[c4], u1 = Ar[c4 + 1];
        v0.x += u0.x; v0.y += u0.y; v0.z += u0.z; v0.w += u0.w;
        v1.x += u1.x; v1.y += u1.y; v1.z += u1.z; v1.w += u1.w;
      }
      float vv[8] = {v0.x, v0.y, v0.z, v0.w, v1.x, v1.y, v1.z, v1.w};
      bf16x8 h, l;
#pragma unroll
      for (int j = 0; j < 8; j++) {
        unsigned short hb = f2bf(vv[j]);
        h[j] = (short)hb;
        l[j] = (short)f2bf(vv[j] - bf2f(hb));
      }
      ahi[mt][ks] = h; alo[mt][ks] = l;
    }
  }
  f32x4 acc[2][8];
#pragma unroll
  for (int mt = 0; mt < 2; mt++)
#pragma unroll
    for (int nt = 0; nt < 8; nt++) acc[mt][nt] = (f32x4){0.f, 0.f, 0.f, 0.f};
#pragma unroll
  for (int ks = 0; ks < 4; ks++) {
#pragma unroll
    for (int nt = 0; nt < 8; nt++) {
      int n = nt * 16 + mrow;
      unsigned int byteoff =
          ((unsigned int)(n * 256 + ks * 64 + g * 16)) ^ (((unsigned int)n & 7u) << 4);
      bf16x8 b = *(const bf16x8*)((const char*)Bt + byteoff);
      acc[0][nt] = __builtin_amdgcn_mfma_f32_16x16x32_bf16(ahi[0][ks], b, acc[0][nt], 0, 0, 0);
      acc[1][nt] = __builtin_amdgcn_mfma_f32_16x16x32_bf16(ahi[1][ks], b, acc[1][nt], 0, 0, 0);
      acc[0][nt] = __builtin_amdgcn_mfma_f32_16x16x32_bf16(alo[0][ks], b, acc[0][nt], 0, 0, 0);
      acc[1][nt] = __builtin_amdgcn_mfma_f32_16x16x32_bf16(alo[1][ks], b, acc[1][nt], 0, 0, 0);
    }
  }
#pragma unroll
  for (int mt = 0; mt < 2; mt++) {
#pragma unroll
    for (int r = 0; r < 4; r++) {
      int row = rbase + mt * 16 + g * 4 + r;
      if (row < N) {
        float sc = rowScale ? rowScale[row] : 1.f;
#pragma unroll
        for (int nt = 0; nt < 4; nt++) {
          int c = nt * 16 + mrow;
          float lo = (acc[mt][nt][r] + (bias ? bias[c] : 0.f)) * sc;
          float hi = (acc[mt][nt + 4][r] + (bias ? bias[c + 64] : 0.f)) * sc;
          Ybf[(size_t)row * 64 + c] = (unsigned int)f2bf(lo) | ((unsigned int)f2bf(hi) << 16);
        }
      }
    }
  }
}

// ---------------- CSR aggregation, wave per node, SPLIT-packed bf16, UNWEIGHTED ----
// Half-wave pairing: lanes 0-31 process even edges, 32-63 odd edges; each lane
// loads uint2 (2 words = 4 features). One load instr covers 2 edges.
// Table word [row][c] = bf16(feature c) | bf16(feature c+64)<<16.
__global__ __launch_bounds__(256) void agg_kernel(const unsigned int* __restrict__ Hf,
                                                  float* __restrict__ out,
                                                  const int* __restrict__ starts,
                                                  const int* __restrict__ rowS,
                                                  const float* __restrict__ dinv,
                                                  const float* __restrict__ bias,
                                                  int C, int relu) {
  int wid = (blockIdx.x * blockDim.x + threadIdx.x) >> 6;
  int lane = threadIdx.x & 63;
  if (wid >= C) return;
  int h = lane >> 5, hl = lane & 31;
  const uint2* Hf2 = (const uint2*)Hf;
  int s = starts[wid], e = starts[wid + 1];
  float dc = dinv[wid];
  float a0 = 0.f, a1 = 0.f, b0 = 0.f, b1 = 0.f;
  for (int base = s; base < e; base += 64) {
    int n = e - base; if (n > 64) n = 64;
    int r = rowS[base + (lane < n ? lane : 0)];
    for (int j = 0; j < n; j += 16) {
#pragma unroll
      for (int u = 0; u < 8; u++) {
        int eidx = j + u * 2 + h;
        bool v = eidx < n;
        int rr = __shfl(r, v ? eidx : 0);
        uint2 pv = Hf2[(size_t)rr * 32 + hl];
        if (!v) { pv.x = 0u; pv.y = 0u; }
        a0 += __uint_as_float(pv.x << 16);
        b0 += __uint_as_float(pv.x & 0xffff0000u);
        a1 += __uint_as_float(pv.y << 16);
        b1 += __uint_as_float(pv.y & 0xffff0000u);
      }
    }
  }
  a0 += __shfl_xor(a0, 32); a1 += __shfl_xor(a1, 32);
  b0 += __shfl_xor(b0, 32); b1 += __shfl_xor(b1, 32);
  int c0 = h * 64 + hl * 2;
  float o0 = (h ? b0 : a0) * dc + bias[c0];
  float o1 = (h ? b1 : a1) * dc + bias[c0 + 1];
  if (relu) { o0 = fmaxf(o0, 0.f); o1 = fmaxf(o1, 0.f); }
  *(float2*)(out + (size_t)wid * 128 + c0) = make_float2(o0, o1);
}

// ---------------- CSR aggregation, BLOCK per node, PAIR-packed bf16, weighted ------
// uint2 half-wave: lanes 0-31 even edges, 32-63 odd edges; lane loads uint2
// (words 2hl,2hl+1 = features 4hl..4hl+3). One load covers 2 edges.
__global__ __launch_bounds__(256) void aggb_kernel(const unsigned int* __restrict__ Hf,
                                                   float* __restrict__ out,
                                                   const int* __restrict__ starts,
                                                   const int* __restrict__ rowS,
                                                   const float* __restrict__ wS,
                                                   const float* __restrict__ dinv,
                                                   const float* __restrict__ bias,
                                                   int C, int relu) {
  int node = blockIdx.x;
  if (node >= C) return;
  int wv = threadIdx.x >> 6, lane = threadIdx.x & 63;
  int h = lane >> 5, hl = lane & 31;
  const uint2* Hf2 = (const uint2*)Hf;
  int s = starts[node], e = starts[node + 1];
  float a0 = 0.f, a1 = 0.f, a2 = 0.f, a3 = 0.f;
  for (int base = s + wv * 64; base < e; base += 256) {
    int n = e - base; if (n > 64) n = 64;
    int moff = base + (lane < n ? lane : 0);
    int r = rowS[moff];
    float w = wS[moff];
    for (int j = 0; j < n; j += 16) {
#pragma unroll
      for (int u = 0; u < 8; u++) {
        int eidx = j + u * 2 + h;
        bool v = eidx < n;
        int rr = __shfl(r, v ? eidx : 0);
        float ww = __shfl(w, v ? eidx : 0);
        if (!v) ww = 0.f;
        uint2 pv = Hf2[(size_t)rr * 32 + hl];
        a0 = fmaf(ww, __uint_as_float(pv.x << 16), a0);
        a1 = fmaf(ww, __uint_as_float(pv.x & 0xffff0000u), a1);
        a2 = fmaf(ww, __uint_as_float(pv.y << 16), a2);
        a3 = fmaf(ww, __uint_as_float(pv.y & 0xffff0000u), a3);
      }
    }
  }
  a0 += __shfl_xor(a0, 32); a1 += __shfl_xor(a1, 32);
  a2 += __shfl_xor(a2, 32); a3 += __shfl_xor(a3, 32);
  __shared__ float4 sh[4][32];
  if (h == 0) sh[wv][hl] = make_float4(a0, a1, a2, a3);
  __syncthreads();
  if (threadIdx.x < 32) {
    float4 v0 = sh[0][threadIdx.x], v1 = sh[1][threadIdx.x];
    float4 v2 = sh[2][threadIdx.x], v3 = sh[3][threadIdx.x];
    float dc = dinv[node];
    int c0 = threadIdx.x * 4;
    float4 bb = *(const float4*)(bias + c0);
    float4 o;
    o.x = (v0.x + v1.x + v2.x + v3.x) * dc + bb.x;
    o.y = (v0.y + v1.y + v2.y + v3.y) * dc + bb.y;
    o.z = (v0.z + v1.z + v2.z + v3.z) * dc + bb.z;
    o.w = (v0.w + v1.w + v2.w + v3.w) * dc + bb.w;
    if (relu) {
      o.x = fmaxf(o.x, 0.f); o.y = fmaxf(o.y, 0.f);
      o.z = fmaxf(o.z, 0.f); o.w = fmaxf(o.w, 0.f);
    }
    *(float4*)(out + (size_t)node * 128 + c0) = o;
  }
}

// ---------------- CSR aggregation, BLOCK per node, PAIR-packed bf16, UNWEIGHTED ----
// uint2 half-wave variant (row weight pre-folded into table).
__global__ __launch_bounds__(256) void aggb1_kernel(const unsigned int* __restrict__ Hf,
                                                    float* __restrict__ out,
                                                    const int* __restrict__ starts,
                                                    const int* __restrict__ rowS,
                                                    const float* __restrict__ dinv,
                                                    const float* __restrict__ bias,
                                                    int C, int relu) {
  int node = blockIdx.x;
  if (node >= C) return;
  int wv = threadIdx.x >> 6, lane = threadIdx.x & 63;
  int h = lane >> 5, hl = lane & 31;
  const uint2* Hf2 = (const uint2*)Hf;
  int s = starts[node], e = starts[node + 1];
  float a0 = 0.f, a1 = 0.f, a2 = 0.f, a3 = 0.f;
  for (int base = s + wv * 64; base < e; base += 256) {
    int n = e - base; if (n > 64) n = 64;
    int r = rowS[base + (lane < n ? lane : 0)];
    for (int j = 0; j < n; j += 16) {
#pragma unroll
      for (int u = 0; u < 8; u++) {
        int eidx = j + u * 2 + h;
        bool v = eidx < n;
        int rr = __shfl(r, v ? eidx : 0);
        uint2 pv = Hf2[(size_t)rr * 32 + hl];
        if (!v) { pv.x = 0u; pv.y = 0u; }
        a0 += __uint_as_float(pv.x << 16);
        a1 += __uint_as_float(pv.x & 0xffff0000u);
        a2 += __uint_as_float(pv.y << 16);
        a3 += __uint_as_float(pv.y & 0xffff0000u);
      }
    }
  }
  a0 += __shfl_xor(a0, 32); a1 += __shfl_xor(a1, 32);
  a2 += __shfl_xor(a2, 32); a3 += __shfl_xor(a3, 32);
  __shared__ float4 sh[4][32];
  if (h == 0) sh[wv][hl] = make_float4(a0, a1, a2, a3);
  __syncthreads();
  if (threadIdx.x < 32) {
    float4 v0 = sh[0][threadIdx.x], v1 = sh[1][threadIdx.x];
    float4 v2 = sh[2][threadIdx.x], v3 = sh[3][threadIdx.x];
    float dc = dinv[node];
    int c0 = threadIdx.x * 4;
    float4 bb = *(const float4*)(bias + c0);
    float4 o;
    o.x = (v0.x + v1.x + v2.x + v3.x) * dc + bb.x;
    o.y = (v0.y + v1.y + v2.y + v3.y) * dc + bb.y;
    o.z = (v0.z + v1.z + v2.z + v3.z) * dc + bb.z;
    o.w = (v0.w + v1.w + v2.w + v3.w) * dc + bb.w;
    if (relu) {
      o.x = fmaxf(o.x, 0.f); o.y = fmaxf(o.y, 0.f);
      o.z = fmaxf(o.z, 0.f); o.w = fmaxf(o.w, 0.f);
    }
    *(float4*)(out + (size_t)node * 128 + c0) = o;
  }
}

// ---------------- seg_mean pooling (unrolled x8, f32 src) ----------------
__global__ __launch_bounds__(256) void pool_kernel(const float* __restrict__ src,
                                                   float* __restrict__ out,
                                                   const int* __restrict__ starts,
                                                   const int* __restrict__ rowS, int C) {
  int wid = (blockIdx.x * blockDim.x + threadIdx.x) >> 6;
  int lane = threadIdx.x & 63;
  if (wid >= C) return;
  int s = starts[wid], e = starts[wid + 1];
  float ax0 = 0.f, ay0 = 0.f, ax1 = 0.f, ay1 = 0.f;
  int m = s;
  for (; m + 7 < e; m += 8) {
    int idx[8];
#pragma unroll
    for (int u = 0; u < 8; u++) idx[u] = rowS[m + u];
#pragma unroll
    for (int u = 0; u < 8; u++) {
      float2 v = *(const float2*)(src + (size_t)idx[u] * 128 + lane * 2);
      if (u & 1) { ax1 += v.x; ay1 += v.y; } else { ax0 += v.x; ay0 += v.y; }
    }
  }
  for (; m < e; m++) {
    int id = rowS[m];
    const float2 v = *(const float2*)(src + (size_t)id * 128 + lane * 2);
    ax0 += v.x; ay0 += v.y;
  }
  float inv = (e > s) ? 1.f / (float)(e - s) : 0.f;
  *(float2*)(out + (size_t)wid * 128 + lane * 2) =
      make_float2((ax0 + ax1) * inv, (ay0 + ay1) * inv);
}

// ---------------- host ----------------

extern "C" void kernel_launch(void* const* d_in, const int* in_sizes, int n_in,
                              void* d_out, int out_size, void* d_ws, size_t ws_size,
                              hipStream_t stream) {
  const float* x     = (const float*)d_in[0];
  const float* W_pre = (const float*)d_in[1];
  const float* b_pre = (const float*)d_in[2];
  const float* W_u0  = (const float*)d_in[3];
  const float* b_u0  = (const float*)d_in[4];
  const float* W_u1  = (const float*)d_in[5];
  const float* b_u1  = (const float*)d_in[6];
  const float* W_u2  = (const float*)d_in[7];
  const float* b_u2  = (const float*)d_in[8];
  const float* W_d0  = (const float*)d_in[9];
  const float* b_d0  = (const float*)d_in[10];
  const float* W_d1  = (const float*)d_in[11];
  const float* b_d1  = (const float*)d_in[12];
  const int* row0 = (const int*)d_in[13];
  const int* col0 = (const int*)d_in[14];
  const int* row1 = (const int*)d_in[16];
  const int* col1 = (const int*)d_in[17];
  const float* ew1 = (const float*)d_in[18];
  const int* row2 = (const int*)d_in[19];
  const int* col2 = (const int*)d_in[20];
  const float* ew2 = (const float*)d_in[21];
  const int* cluster1 = (const int*)d_in[22];
  const int* cluster2 = (const int*)d_in[23];
  int E0 = in_sizes[13], E1 = in_sizes[16], E2 = in_sizes[19];
  float* out = (float*)d_out;
  int Ttot = E0 + E1 + E2 + kN0 + kC1;
  int Etot = E0 + E1 + E2;

  char* basep = (char*)d_ws;
  size_t off = 0;
  auto alloc = [&](size_t bytes) -> char* {
    char* p = basep + off;
    off = (off + bytes + 255) & ~(size_t)255;
    return p;
  };
  // zero-init: bucketCnt only
  int* bucketCnt = (int*)alloc((size_t)NBK * 4);
  size_t zero_bytes = off;
  // persistent
  int* bucketStart = (int*)alloc((size_t)(NBK + 1) * 4);
  int* cursor      = (int*)alloc((size_t)NBK * 4);
  int* startsg     = (int*)alloc((size_t)(NTOT + 1) * 4);
  int* rowS  = (int*)alloc((size_t)Ttot * 4);
  float* ewS = (float*)alloc((size_t)(E1 + E2) * 4);
  float* ewSm = ewS - E0;
  float* dinv0  = (float*)alloc((size_t)kN0 * 4);
  float* dinv1w = (float*)alloc((size_t)kC1 * 4);
  float* dinv1o = (float*)alloc((size_t)kC1 * 4);
  float* dinv2  = (float*)alloc((size_t)kC2 * 4);
  // --- overlay: part (dead after p4) aliases everything written after p4 ---
  size_t watermark = off;
  int4* part = (int4*)alloc((size_t)Ttot * 16);
  off = watermark;
  float* wAll = (float*)alloc((size_t)Etot * 4);
  float* Wf   = (float*)alloc((size_t)128 * 128 * 4);
  float* bfv  = (float*)alloc((size_t)128 * 4);
  float* A    = (float*)alloc((size_t)kN0 * HH * 4);
  float* s1a  = (float*)alloc((size_t)kC1 * HH * 4);
  float* s1b  = (float*)alloc((size_t)kC1 * HH * 4);
  float* s2a  = (float*)alloc((size_t)kC2 * HH * 4);
  unsigned int* s1bb = (unsigned int*)alloc((size_t)kC1 * 64 * 4);
  unsigned int* s2bb = (unsigned int*)alloc((size_t)kC2 * 64 * 4);
  unsigned int* s1cb = (unsigned int*)alloc((size_t)kC1 * 64 * 4);
  unsigned int* tb   = (unsigned int*)alloc((size_t)kN0 * 64 * 4);
  unsigned int* t0   = (unsigned int*)d_out;  // bf16 scratch in d_out (dead before final write)

  hipMemsetAsync(d_ws, 0, zero_bytes, stream);

  auto cdiv = [](int a, int b) { return (a + b - 1) / b; };

  // CSR build
  p1_kernel<<<256, 256, 0, stream>>>(col0, col1, col2, cluster1, cluster2, E0, E1, E2, bucketCnt);
  p2_kernel<<<1, 1024, 0, stream>>>(bucketCnt, bucketStart, cursor, startsg, Ttot);
  p3_kernel<<<cdiv(Ttot, 4096), 256, 0, stream>>>(col0, col1, col2, cluster1, cluster2,
                                                  row0, row1, row2, ew1, ew2, E0, E1, E2,
                                                  cursor, part);
  p4_kernel<<<NBK, 256, 0, stream>>>(bucketStart, part, startsg, rowS, ewSm);
  dinv_kernel<<<cdiv((kC1 + kC2) * 64, 256), 256, 0, stream>>>(startsg, ewSm, dinv0, dinv1w,
                                                               dinv1o, dinv2);
  wprep_kernel<<<cdiv(E1 + E2, 256), 256, 0, stream>>>(rowS, ewSm, dinv1w, dinv2,
                                                       E0, E1, E2, wAll);

  // Fused pre+u0 weights: Wf = W_pre @ W_u0 (128x128), bfv = b_pre @ W_u0 (1x128)
  matmul_kernel<<<cdiv(128, 32), 256, 0, stream>>>(W_pre, nullptr, nullptr, W_u0, nullptr,
                                                   nullptr, Wf, nullptr, 128);
  matmul_kernel<<<1, 256, 0, stream>>>(b_pre, nullptr, nullptr, W_u0, nullptr,
                                       nullptr, bfv, nullptr, 1);
  // t0 = dinv0[row] * (x@Wf + bfv) -> bf16 split-packed (d_out scratch)
  mfma_gemm_kernel<<<cdiv(kN0, 128), 256, 0, stream>>>(x, nullptr, nullptr, Wf, bfv, dinv0,
                                                       t0, kN0);
  // x0 = relu(agg0(t0) + b_u0) -> A   (unweighted; dinv0 folded into table)
  agg_kernel<<<cdiv(kN0, 4), 256, 0, stream>>>(t0, A, startsg, rowS, dinv0, b_u0, kN0, 1);
  // x1m = seg_mean(x0, cluster1) -> s1a
  pool_kernel<<<cdiv(kC1, 4), 256, 0, stream>>>(A, s1a, startsg + B2, rowS, kC1);
  // t1 = x1m@W_u1 -> bf16 s1bb (pair-packed)
  matmul_kernel<<<cdiv(kC1, 32), 256, 0, stream>>>(s1a, nullptr, nullptr, W_u1, nullptr,
                                                   nullptr, nullptr, s1bb, kC1);
  // x1 = relu(agg1_w(t1) + b_u1) -> s1a
  aggb_kernel<<<kC1, 256, 0, stream>>>(s1bb, s1a, startsg + B0, rowS, wAll, dinv1w, b_u1, kC1, 1);
  // x2m = seg_mean(x1, cluster2) -> s2a
  pool_kernel<<<cdiv(kC2, 4), 256, 0, stream>>>(s1a, s2a, startsg + B3, rowS, kC2);
  // t2 = x2m@W_u2 -> bf16 s2bb
  matmul_kernel<<<cdiv(kC2, 32), 256, 0, stream>>>(s2a, nullptr, nullptr, W_u2, nullptr,
                                                   nullptr, nullptr, s2bb, kC2);
  // x2 = relu(agg2_w(t2) + b_u2) -> s2a
  aggb_kernel<<<kC2, 256, 0, stream>>>(s2bb, s2a, startsg + B1, rowS, wAll, dinv2, b_u2, kC2, 1);
  // fused: d1o[row] * ((x1 + x2[cluster2]) @ W_d1) -> bf16 s1cb
  matmul_kernel<<<cdiv(kC1, 32), 256, 0, stream>>>(s1a, s2a, cluster2, W_d1, nullptr,
                                                   dinv1o, nullptr, s1cb, kC1);
  // y1 = relu(agg1_ones(s1cb) + b_d1) -> s1b   (unweighted; d1o folded into table)
  aggb1_kernel<<<kC1, 256, 0, stream>>>(s1cb, s1b, startsg + B0, rowS, dinv1o, b_d1, kC1, 1);
  // fused addgather: tb = dinv0[row] * ((x0 + y1[cluster1]) @ W_d0) -> bf16 split-packed
  mfma_gemm_kernel<<<cdiv(kN0, 128), 256, 0, stream>>>(A, s1b, cluster1, W_d0, nullptr, dinv0,
                                                       tb, kN0);
  // final: out = agg0(tb) + b_d0 (no relu; unweighted)
  agg_kernel<<<cdiv(kN0, 4), 256, 0, stream>>>(tb, out, startsg, rowS, dinv0, b_d0, kN0, 0);
}